// Round 12
// baseline (424.495 us; speedup 1.0000x reference)
//
#include <hip/hip_runtime.h>
#include <stdint.h>

#define NSCENE 16
#define NPED 32
#define NB_TOT 512
#define HD 64
#define ED 64
#define D1 8192
#define BOTN 1024

typedef unsigned short ushort_t;
typedef __attribute__((ext_vector_type(4))) float f32x4;
typedef __attribute__((ext_vector_type(16))) float f32x16;
typedef __attribute__((ext_vector_type(8))) __bf16 bf16x8;  // gfx950 mfma operand (V8y)
typedef __attribute__((ext_vector_type(4))) unsigned int u32x4;
typedef __attribute__((ext_vector_type(2))) unsigned int u32x2;

__device__ __forceinline__ float bf2f(ushort_t u) {
  union { unsigned int i; float f; } x;
  x.i = ((unsigned int)u) << 16;
  return x.f;
}

__device__ __forceinline__ ushort_t f2bf(float f) {
  union { float f; unsigned int i; } x;
  x.f = f;
  unsigned int u = x.i + 0x7fffu + ((x.i >> 16) & 1u);
  return (ushort_t)(u >> 16);
}

// pack two f32 -> two bf16 RNE (lo in bits [15:0])
__device__ __forceinline__ unsigned int packbf(float lo, float hi) {
#if __has_builtin(__builtin_amdgcn_cvt_pk_bf16_f32)
  typedef __attribute__((ext_vector_type(2))) __bf16 bf16x2_t;
  union { bf16x2_t v; unsigned int u; } x;
  x.v = __builtin_amdgcn_cvt_pk_bf16_f32(lo, hi);
  return x.u;
#else
  return (unsigned int)f2bf(lo) | ((unsigned int)f2bf(hi) << 16);
#endif
}

// unpack u32 holding 2 bf16 -> 2 f32
__device__ __forceinline__ void unpk(unsigned int u, float& lo, float& hi) {
  union { unsigned int i; float f; } a, b;
  a.i = u << 16;
  b.i = u & 0xffff0000u;
  lo = a.f;
  hi = b.f;
}

__device__ __forceinline__ float clip1(float x) {
  return fminf(fmaxf(x, -1.f), 1.f);
}

// async global->LDS DMA, 16B/lane; casts through integers (legal reinterpret).
// HW: LDS dest = wave-uniform base + lane*16 — caller arranges that.
__device__ __forceinline__ void async_load16(const void* g, void* l) {
  __builtin_amdgcn_global_load_lds(
      (const __attribute__((address_space(1))) unsigned int*)(unsigned long long)g,
      (__attribute__((address_space(3))) unsigned int*)(unsigned int)(unsigned long long)l,
      16, 0, 0);
}

// ---------------------------------------------------------------------------
// k_pre: ALL preprocessing in one kernel of independent blocks.
//   bid <  2048 : W2 transpose tile (64k x 64n)  -> W2T
//   bid <  2304 : hc block (16 j-rows x 1024 k, hbias inline) -> hcb
//   bid <  2336 : M0/M1 fold (256 k each)
//   bid == 2336 : epf/b2f canonicalize + *flag
// Every block detects input dtype inline (1 KB of W1, LDS reduce).
// ---------------------------------------------------------------------------
__global__ __launch_bounds__(256) void k_pre(
    const void* __restrict__ hv_, const void* __restrict__ end_posv,
    const void* __restrict__ W_spv, const void* __restrict__ b_spv,
    const void* __restrict__ W1v, const void* __restrict__ b1v,
    const void* __restrict__ W2v, const void* __restrict__ b2v,
    int* __restrict__ flag, float* __restrict__ epf, float* __restrict__ b2f,
    float* __restrict__ M0, float* __restrict__ M1,
    ushort_t* __restrict__ hcb, ushort_t* __restrict__ W2T) {
  __shared__ ushort_t tile[64][72];
  __shared__ int cnt[256];
  __shared__ int isbf_sh;
  const int t = threadIdx.x;
  const int bid = blockIdx.x;

  // ---- inline dtype detection ----
  {
    const ushort_t* wu = (const ushort_t*)W1v;
    unsigned int u = wu[2 * t];
    int e = (u >> 7) & 0xff;
    cnt[t] = (e >= 90 && e <= 140) ? 1 : 0;
    __syncthreads();
    for (int ofs = 128; ofs > 0; ofs >>= 1) {
      if (t < ofs) cnt[t] += cnt[t + ofs];
      __syncthreads();
    }
    if (t == 0) isbf_sh = (cnt[0] >= 128) ? 1 : 0;
    __syncthreads();
  }
  const int isbf = isbf_sh;

  if (bid < 2048) {
    // ================= W2 transpose =================
    const int kt = bid & 127, nt = bid >> 7;
    const int r = t >> 3, c8 = (t & 7) * 8;
#pragma unroll
    for (int i = 0; i < 2; ++i) {
      int row = i * 32 + r;
      size_t base = (size_t)(kt * 64 + row) * BOTN + nt * 64 + c8;
      if (isbf) {
        u32x4 v = *(const u32x4*)((const ushort_t*)W2v + base);
        *(u32x4*)&tile[row][c8] = v;
      } else {
        const float* src = (const float*)W2v + base;
        float4 w0 = *(const float4*)src;
        float4 w1 = *(const float4*)(src + 4);
        u32x4 pk;
        pk.x = packbf(w0.x, w0.y);
        pk.y = packbf(w0.z, w0.w);
        pk.z = packbf(w1.x, w1.y);
        pk.w = packbf(w1.z, w1.w);
        *(u32x4*)&tile[row][c8] = pk;
      }
    }
    __syncthreads();
#pragma unroll
    for (int i = 0; i < 2; ++i) {
      int nrow = i * 32 + r;
      union { ushort_t us[8]; u32x4 v; } pk;
#pragma unroll
      for (int jj = 0; jj < 8; ++jj) pk.us[jj] = tile[c8 + jj][nrow];
      *(u32x4*)(W2T + (size_t)(nt * 64 + nrow) * D1 + kt * 64 + c8) = pk.v;
    }
  } else if (bid < 2304) {
    // ================= hc: hcb[j][k] = hbias[k] + h[j]@W1[64:] =============
    const int idx = bid - 2048;
    const int kb = idx & 7, jt = idx >> 3;
    const int kbase = kb * 1024 + t * 4;
    // ---- hbias inline: b1[k] + sum_e b_sp[e]*W1[e][k] ----
    float hb0, hb1, hb2, hb3;
    if (isbf) {
      const ushort_t* b1u = (const ushort_t*)b1v;
      const ushort_t* bspu = (const ushort_t*)b_spv;
      const ushort_t* wp = (const ushort_t*)W1v + kbase;
      hb0 = bf2f(b1u[kbase]); hb1 = bf2f(b1u[kbase + 1]);
      hb2 = bf2f(b1u[kbase + 2]); hb3 = bf2f(b1u[kbase + 3]);
      for (int e = 0; e < ED; ++e) {
        float bs = bf2f(bspu[e]);
        u32x2 wv = *(const u32x2*)(wp + (size_t)e * D1);
        float w0, w1, w2, w3;
        unpk(wv.x, w0, w1); unpk(wv.y, w2, w3);
        hb0 += bs * w0; hb1 += bs * w1; hb2 += bs * w2; hb3 += bs * w3;
      }
    } else {
      const float* b1f = (const float*)b1v;
      const float* bspf = (const float*)b_spv;
      const float* wp = (const float*)W1v + kbase;
      hb0 = b1f[kbase]; hb1 = b1f[kbase + 1];
      hb2 = b1f[kbase + 2]; hb3 = b1f[kbase + 3];
      for (int e = 0; e < ED; ++e) {
        float bs = bspf[e];
        float4 w = *(const float4*)(wp + (size_t)e * D1);
        hb0 += bs * w.x; hb1 += bs * w.y; hb2 += bs * w.z; hb3 += bs * w.w;
      }
    }
    // ---- main accumulation over h ----
    float acc[16][4];
#pragma unroll
    for (int j = 0; j < 16; ++j)
#pragma unroll
      for (int c = 0; c < 4; ++c) acc[j][c] = 0.f;
    if (isbf) {
      const ushort_t* wp = (const ushort_t*)W1v + (size_t)ED * D1 + kbase;
      const ushort_t* hp = (const ushort_t*)hv_ + jt * 16 * HD;
      for (int hh = 0; hh < HD; ++hh) {
        u32x2 wv = *(const u32x2*)(wp + (size_t)hh * D1);
        float w0, w1, w2, w3;
        unpk(wv.x, w0, w1); unpk(wv.y, w2, w3);
#pragma unroll
        for (int j = 0; j < 16; ++j) {
          float hj = bf2f(hp[j * HD + hh]);
          acc[j][0] += hj * w0;
          acc[j][1] += hj * w1;
          acc[j][2] += hj * w2;
          acc[j][3] += hj * w3;
        }
      }
    } else {
      const float* wp = (const float*)W1v + (size_t)ED * D1 + kbase;
      const float* hp = (const float*)hv_ + jt * 16 * HD;
#pragma unroll 4
      for (int hh = 0; hh < HD; ++hh) {
        float4 w = *(const float4*)(wp + (size_t)hh * D1);
#pragma unroll
        for (int j = 0; j < 16; ++j) {
          float hj = hp[j * HD + hh];
          acc[j][0] += hj * w.x;
          acc[j][1] += hj * w.y;
          acc[j][2] += hj * w.z;
          acc[j][3] += hj * w.w;
        }
      }
    }
#pragma unroll
    for (int j = 0; j < 16; ++j) {
      u32x2 pk;
      pk.x = packbf(acc[j][0] + hb0, acc[j][1] + hb1);
      pk.y = packbf(acc[j][2] + hb2, acc[j][3] + hb3);
      *(u32x2*)(hcb + (size_t)(jt * 16 + j) * D1 + kbase) = pk;
    }
  } else if (bid < 2336) {
    // ================= M0/M1 fold =================
    const int k = (bid - 2304) * 256 + t;
    float m0 = 0.f, m1 = 0.f;
    if (isbf) {
      const ushort_t* Wspu = (const ushort_t*)W_spv;
      const ushort_t* W1u = (const ushort_t*)W1v;
      for (int e = 0; e < ED; ++e) {
        float w = bf2f(W1u[e * D1 + k]);
        m0 += bf2f(Wspu[e]) * w;
        m1 += bf2f(Wspu[ED + e]) * w;
      }
    } else {
      const float* Wspf = (const float*)W_spv;
      const float* W1f = (const float*)W1v;
      for (int e = 0; e < ED; ++e) {
        float w = W1f[e * D1 + k];
        m0 += Wspf[e] * w;
        m1 += Wspf[ED + e] * w;
      }
    }
    M0[k] = m0;
    M1[k] = m1;
  } else {
    // ================= epf / b2f / flag =================
    if (t == 0) *flag = isbf;
    const ushort_t* epu = (const ushort_t*)end_posv;
    const float* epff = (const float*)end_posv;
    const ushort_t* b2u = (const ushort_t*)b2v;
    const float* b2ff = (const float*)b2v;
    for (int i = t; i < 1024; i += 256) {
      epf[i] = isbf ? bf2f(epu[i]) : epff[i];
      b2f[i] = isbf ? bf2f(b2u[i]) : b2ff[i];
    }
  }
}

// ---------------------------------------------------------------------------
// k_gemm v7: R6 structure (BM=64 BN=512 BK=64, 2 blocks/CU, DMA+swizzle)
// with 32x32x16 MFMA. Wave tile 64m x 128n = 2 m-tiles (a=abase+mt, rows=b
// 0..31) x 4 n-tiles of 32. Same A/B LDS content as R6; only fragment
// indexing + MFMA shape + epilogue change. Max-pool over b collapses WITHIN
// the 32x32 tile: C/D row = b (col=lane&31, row=(reg&3)+8*(reg>>2)+
// 4*(lane>>5), m74/m101-verified) -> max over 16 regs + shfl_xor(32).
// ---------------------------------------------------------------------------
#define ASTR 72  // A-tile LDS row stride in shorts (144B)
__global__ __launch_bounds__(256, 2) void k_gemm(
    const ushort_t* __restrict__ hcb, const float* __restrict__ M0f,
    const float* __restrict__ M1f, const ushort_t* __restrict__ W2T,
    const float* __restrict__ epf, const float* __restrict__ b2f,
    const int* __restrict__ flag, void* __restrict__ outv) {
  __shared__ ushort_t aLds[64 * ASTR];   // 9.2 KB: rows = mt*32 + b
  __shared__ ushort_t bLds[512 * 64];    // 64 KB, unpadded (DMA dest), swizzled
  __shared__ float2 rrLds[64];

  const int t = threadIdx.x;
  const int w = t >> 6;
  const int lane = t & 63;
  const int nb = blockIdx.x & 1;
  const int mb = blockIdx.x >> 1;  // 0..255
  const int s = mb >> 4;
  const int abase = (mb & 15) * 2;
  const int isbf = *flag;

  if (t < 64) {
    int g = t >> 5, b = t & 31;
    int pa = s * 32 + abase + g, pb = s * 32 + b;
    float r0 = epf[pb * 2] - epf[pa * 2];
    float r1 = epf[pb * 2 + 1] - epf[pa * 2 + 1];
    rrLds[t] = make_float2(clip1(r0), clip1(r1));
  }
  __syncthreads();

  const int bq = t >> 3;  // 0..31 : hc row (b) this thread generates
  const int kc = t & 7;   // 0..7  : 8-short chunk within BK
  float rr0[2], rr1[2];
#pragma unroll
  for (int g = 0; g < 2; ++g) {
    float2 v = rrLds[g * 32 + bq];
    rr0[g] = v.x;
    rr1[g] = v.y;
  }

  const ushort_t* hcRow = hcb + (size_t)(s * 32 + bq) * D1 + kc * 8;
  const float* m0p = M0f + kc * 8;
  const float* m1p = M1f + kc * 8;

  // B DMA addressing: lane covers row (i*32 + w*8 + (lane>>3)), LDS slot lane&7,
  // so it must FETCH global chunk (lane&7) ^ (lane>>3): slot s holds chunk
  // s ^ (row&7).
  const int rowl = w * 8 + (lane >> 3);
  const int chl = (lane & 7) ^ (lane >> 3);
  const ushort_t* bGlob = W2T + (size_t)(nb * 512 + rowl) * D1 + chl * 8;
  ushort_t* bLdsLane = bLds + (size_t)rowl * 64 + (lane & 7) * 8;  // base + lane*16B

  ushort_t* aW = aLds + bq * ASTR + kc * 8;  // + g*32*ASTR

  f32x16 acc[2][4];
#pragma unroll
  for (int mt = 0; mt < 2; ++mt)
#pragma unroll
    for (int nt = 0; nt < 4; ++nt)
#pragma unroll
      for (int i = 0; i < 16; ++i) acc[mt][nt][i] = 0.f;

  // ---- 32x32x16 fragment indexing ----
  const int r32 = lane & 31, half = lane >> 5, r7 = r32 & 7;
  const ushort_t* aR32 = aLds + r32 * ASTR + half * 8;       // + mt*32*ASTR + ks*16
  const ushort_t* bR32 = bLds + (w * 128 + r32) * 64;        // + nt*2048 + slot*8

  for (int kk = 0; kk < D1 / 64; ++kk) {
    const int k0 = kk * 64;
    // ---- B tile: async DMA global->LDS (16B/lane, 16 issues) ----
#pragma unroll
    for (int i = 0; i < 16; ++i)
      async_load16(bGlob + (size_t)i * 32 * D1 + k0, bLdsLane + i * 32 * 64);

    // ---- A-gen: relu(hc + r0*M0 + r1*M1), pack bf16, write LDS ----
    u32x4 hv = *(const u32x4*)(hcRow + k0);
    float h0, h1, h2, h3, h4, h5, h6, h7;
    unpk(hv.x, h0, h1); unpk(hv.y, h2, h3);
    unpk(hv.z, h4, h5); unpk(hv.w, h6, h7);
    float4 a0 = *(const float4*)(m0p + k0);
    float4 a1 = *(const float4*)(m0p + k0 + 4);
    float4 c0 = *(const float4*)(m1p + k0);
    float4 c1 = *(const float4*)(m1p + k0 + 4);
#pragma unroll
    for (int g = 0; g < 2; ++g) {
      float r0 = rr0[g], r1 = rr1[g];
      float v0 = fmaxf(h0 + r0 * a0.x + r1 * c0.x, 0.f);
      float v1 = fmaxf(h1 + r0 * a0.y + r1 * c0.y, 0.f);
      float v2 = fmaxf(h2 + r0 * a0.z + r1 * c0.z, 0.f);
      float v3 = fmaxf(h3 + r0 * a0.w + r1 * c0.w, 0.f);
      float v4 = fmaxf(h4 + r0 * a1.x + r1 * c1.x, 0.f);
      float v5 = fmaxf(h5 + r0 * a1.y + r1 * c1.y, 0.f);
      float v6 = fmaxf(h6 + r0 * a1.z + r1 * c1.z, 0.f);
      float v7 = fmaxf(h7 + r0 * a1.w + r1 * c1.w, 0.f);
      u32x4 pk;
      pk.x = packbf(v0, v1);
      pk.y = packbf(v2, v3);
      pk.z = packbf(v4, v5);
      pk.w = packbf(v6, v7);
      *(u32x4*)(aW + g * 32 * ASTR) = pk;
    }
    __syncthreads();  // drains DMA (vmcnt) + A-gen ds_writes

    // ---- mfma phase: 4 ksteps of K=16, 2 mt x 4 nt 32x32x16 ----
#pragma unroll
    for (int ks = 0; ks < 4; ++ks) {
      bf16x8 af[2], bfr[4];
#pragma unroll
      for (int mt = 0; mt < 2; ++mt)
        af[mt] = *(const bf16x8*)(aR32 + mt * 32 * ASTR + ks * 16);
      const int slk = (((ks * 2 + half) ^ r7)) * 8;
#pragma unroll
      for (int nt = 0; nt < 4; ++nt)
        bfr[nt] = *(const bf16x8*)(bR32 + nt * 2048 + slk);
#pragma unroll
      for (int mt = 0; mt < 2; ++mt)
#pragma unroll
        for (int nt = 0; nt < 4; ++nt)
          acc[mt][nt] = __builtin_amdgcn_mfma_f32_32x32x16_bf16(
              af[mt], bfr[nt], acc[mt][nt], 0, 0, 0);
    }
    __syncthreads();
  }

  // ---- epilogue: max over b = max over tile rows (16 regs + shfl 32) ----
#pragma unroll
  for (int mt = 0; mt < 2; ++mt) {
    int orow = s * 32 + abase + mt;
#pragma unroll
    for (int nt = 0; nt < 4; ++nt) {
      f32x16 x = acc[mt][nt];
      float v = x[0];
#pragma unroll
      for (int i = 1; i < 16; ++i) v = fmaxf(v, x[i]);
      v = fmaxf(v, __shfl_xor(v, 32, 64));
      if (lane < 32) {
        int col = nb * 512 + w * 128 + nt * 32 + lane;
        float o = fmaxf(v + b2f[col], 0.f);
        if (isbf)
          ((ushort_t*)outv)[(size_t)orow * BOTN + col] = f2bf(o);
        else
          ((float*)outv)[(size_t)orow * BOTN + col] = o;
      }
    }
  }
}

extern "C" void kernel_launch(void* const* d_in, const int* in_sizes, int n_in,
                              void* d_out, int out_size, void* d_ws, size_t ws_size,
                              hipStream_t stream) {
  (void)in_sizes; (void)n_in; (void)out_size; (void)ws_size;
  const void* h_states = d_in[0];
  const void* end_pos = d_in[1];
  // d_in[2] rel_pos: unused by reference; d_in[3] seq_start_end: fixed equal scenes
  const void* W_sp = d_in[4];
  const void* b_sp = d_in[5];
  const void* W1 = d_in[6];
  const void* b1 = d_in[7];
  const void* W2 = d_in[8];
  const void* b2 = d_in[9];

  char* ws = (char*)d_ws;
  ushort_t* hcb = (ushort_t*)ws;                         // 8 MB  (512x8192 bf16)
  ushort_t* W2T = (ushort_t*)(ws + (8u << 20));          // 16 MB (1024x8192 bf16)
  float* M0f = (float*)(ws + (24u << 20));               // 32 KB
  float* M1f = (float*)(ws + (24u << 20) + 32768);       // 32 KB
  float* epf = (float*)(ws + (24u << 20) + 98304);       // 4 KB
  float* b2f = (float*)(ws + (24u << 20) + 102400);      // 4 KB
  int* flag = (int*)(ws + (24u << 20) + 106496);         // 4 B

  k_pre<<<dim3(2337), dim3(256), 0, stream>>>(
      h_states, end_pos, W_sp, b_sp, W1, b1, W2, b2,
      flag, epf, b2f, M0f, M1f, hcb, W2T);
  k_gemm<<<dim3(512), dim3(256), 0, stream>>>(hcb, M0f, M1f, W2T, epf, b2f, flag, d_out);
}

// Round 13
// 406.165 us; speedup vs baseline: 1.0451x; 1.0451x over previous
//
#include <hip/hip_runtime.h>
#include <stdint.h>

#define NSCENE 16
#define NPED 32
#define NB_TOT 512
#define HD 64
#define ED 64
#define D1 8192
#define BOTN 1024

typedef unsigned short ushort_t;
typedef __attribute__((ext_vector_type(4))) float f32x4;
typedef __attribute__((ext_vector_type(8))) __bf16 bf16x8;  // gfx950 mfma operand (V8y)
typedef __attribute__((ext_vector_type(4))) unsigned int u32x4;
typedef __attribute__((ext_vector_type(2))) unsigned int u32x2;

__device__ __forceinline__ float bf2f(ushort_t u) {
  union { unsigned int i; float f; } x;
  x.i = ((unsigned int)u) << 16;
  return x.f;
}

__device__ __forceinline__ ushort_t f2bf(float f) {
  union { float f; unsigned int i; } x;
  x.f = f;
  unsigned int u = x.i + 0x7fffu + ((x.i >> 16) & 1u);
  return (ushort_t)(u >> 16);
}

// pack two f32 -> two bf16 RNE (lo in bits [15:0])
__device__ __forceinline__ unsigned int packbf(float lo, float hi) {
#if __has_builtin(__builtin_amdgcn_cvt_pk_bf16_f32)
  typedef __attribute__((ext_vector_type(2))) __bf16 bf16x2_t;
  union { bf16x2_t v; unsigned int u; } x;
  x.v = __builtin_amdgcn_cvt_pk_bf16_f32(lo, hi);
  return x.u;
#else
  return (unsigned int)f2bf(lo) | ((unsigned int)f2bf(hi) << 16);
#endif
}

// unpack u32 holding 2 bf16 -> 2 f32
__device__ __forceinline__ void unpk(unsigned int u, float& lo, float& hi) {
  union { unsigned int i; float f; } a, b;
  a.i = u << 16;
  b.i = u & 0xffff0000u;
  lo = a.f;
  hi = b.f;
}

__device__ __forceinline__ float clip1(float x) {
  return fminf(fmaxf(x, -1.f), 1.f);
}

// async global->LDS DMA, 16B/lane; casts through integers (legal reinterpret).
// HW: LDS dest = wave-uniform base + lane*16 — caller arranges that.
__device__ __forceinline__ void async_load16(const void* g, void* l) {
  __builtin_amdgcn_global_load_lds(
      (const __attribute__((address_space(1))) unsigned int*)(unsigned long long)g,
      (__attribute__((address_space(3))) unsigned int*)(unsigned int)(unsigned long long)l,
      16, 0, 0);
}

// ---------------------------------------------------------------------------
// k_pre: ALL preprocessing in one kernel of independent blocks.
// Long-pole hc blocks FIRST so they don't form the dispatch tail:
//   bid <   256 : hc block (16 j-rows x 1024 k, hbias inline) -> hcb
//   bid <  2304 : W2 transpose tile (64k x 64n)  -> W2T
//   bid <  2336 : M0/M1 fold (256 k each)
//   bid == 2336 : epf/b2f canonicalize + *flag
// Every block detects input dtype inline (1 KB of W1, LDS reduce).
// ---------------------------------------------------------------------------
__global__ __launch_bounds__(256) void k_pre(
    const void* __restrict__ hv_, const void* __restrict__ end_posv,
    const void* __restrict__ W_spv, const void* __restrict__ b_spv,
    const void* __restrict__ W1v, const void* __restrict__ b1v,
    const void* __restrict__ W2v, const void* __restrict__ b2v,
    int* __restrict__ flag, float* __restrict__ epf, float* __restrict__ b2f,
    float* __restrict__ M0, float* __restrict__ M1,
    ushort_t* __restrict__ hcb, ushort_t* __restrict__ W2T) {
  __shared__ ushort_t tile[64][72];
  __shared__ int cnt[256];
  __shared__ int isbf_sh;
  const int t = threadIdx.x;
  const int bid = blockIdx.x;

  // ---- inline dtype detection ----
  {
    const ushort_t* wu = (const ushort_t*)W1v;
    unsigned int u = wu[2 * t];
    int e = (u >> 7) & 0xff;
    cnt[t] = (e >= 90 && e <= 140) ? 1 : 0;
    __syncthreads();
    for (int ofs = 128; ofs > 0; ofs >>= 1) {
      if (t < ofs) cnt[t] += cnt[t + ofs];
      __syncthreads();
    }
    if (t == 0) isbf_sh = (cnt[0] >= 128) ? 1 : 0;
    __syncthreads();
  }
  const int isbf = isbf_sh;

  if (bid < 256) {
    // ================= hc: hcb[j][k] = hbias[k] + h[j]@W1[64:] =============
    const int kb = bid & 7, jt = bid >> 3;
    const int kbase = kb * 1024 + t * 4;
    // ---- hbias inline: b1[k] + sum_e b_sp[e]*W1[e][k] ----
    float hb0, hb1, hb2, hb3;
    if (isbf) {
      const ushort_t* b1u = (const ushort_t*)b1v;
      const ushort_t* bspu = (const ushort_t*)b_spv;
      const ushort_t* wp = (const ushort_t*)W1v + kbase;
      hb0 = bf2f(b1u[kbase]); hb1 = bf2f(b1u[kbase + 1]);
      hb2 = bf2f(b1u[kbase + 2]); hb3 = bf2f(b1u[kbase + 3]);
      for (int e = 0; e < ED; ++e) {
        float bs = bf2f(bspu[e]);
        u32x2 wv = *(const u32x2*)(wp + (size_t)e * D1);
        float w0, w1, w2, w3;
        unpk(wv.x, w0, w1); unpk(wv.y, w2, w3);
        hb0 += bs * w0; hb1 += bs * w1; hb2 += bs * w2; hb3 += bs * w3;
      }
    } else {
      const float* b1f = (const float*)b1v;
      const float* bspf = (const float*)b_spv;
      const float* wp = (const float*)W1v + kbase;
      hb0 = b1f[kbase]; hb1 = b1f[kbase + 1];
      hb2 = b1f[kbase + 2]; hb3 = b1f[kbase + 3];
      for (int e = 0; e < ED; ++e) {
        float bs = bspf[e];
        float4 w = *(const float4*)(wp + (size_t)e * D1);
        hb0 += bs * w.x; hb1 += bs * w.y; hb2 += bs * w.z; hb3 += bs * w.w;
      }
    }
    // ---- main accumulation over h ----
    float acc[16][4];
#pragma unroll
    for (int j = 0; j < 16; ++j)
#pragma unroll
      for (int c = 0; c < 4; ++c) acc[j][c] = 0.f;
    if (isbf) {
      const ushort_t* wp = (const ushort_t*)W1v + (size_t)ED * D1 + kbase;
      const ushort_t* hp = (const ushort_t*)hv_ + jt * 16 * HD;
      for (int hh = 0; hh < HD; ++hh) {
        u32x2 wv = *(const u32x2*)(wp + (size_t)hh * D1);
        float w0, w1, w2, w3;
        unpk(wv.x, w0, w1); unpk(wv.y, w2, w3);
#pragma unroll
        for (int j = 0; j < 16; ++j) {
          float hj = bf2f(hp[j * HD + hh]);
          acc[j][0] += hj * w0;
          acc[j][1] += hj * w1;
          acc[j][2] += hj * w2;
          acc[j][3] += hj * w3;
        }
      }
    } else {
      const float* wp = (const float*)W1v + (size_t)ED * D1 + kbase;
      const float* hp = (const float*)hv_ + jt * 16 * HD;
#pragma unroll 4
      for (int hh = 0; hh < HD; ++hh) {
        float4 w = *(const float4*)(wp + (size_t)hh * D1);
#pragma unroll
        for (int j = 0; j < 16; ++j) {
          float hj = hp[j * HD + hh];
          acc[j][0] += hj * w.x;
          acc[j][1] += hj * w.y;
          acc[j][2] += hj * w.z;
          acc[j][3] += hj * w.w;
        }
      }
    }
#pragma unroll
    for (int j = 0; j < 16; ++j) {
      u32x2 pk;
      pk.x = packbf(acc[j][0] + hb0, acc[j][1] + hb1);
      pk.y = packbf(acc[j][2] + hb2, acc[j][3] + hb3);
      *(u32x2*)(hcb + (size_t)(jt * 16 + j) * D1 + kbase) = pk;
    }
  } else if (bid < 2304) {
    // ================= W2 transpose =================
    const int idx = bid - 256;
    const int kt = idx & 127, nt = idx >> 7;
    const int r = t >> 3, c8 = (t & 7) * 8;
#pragma unroll
    for (int i = 0; i < 2; ++i) {
      int row = i * 32 + r;
      size_t base = (size_t)(kt * 64 + row) * BOTN + nt * 64 + c8;
      if (isbf) {
        u32x4 v = *(const u32x4*)((const ushort_t*)W2v + base);
        *(u32x4*)&tile[row][c8] = v;
      } else {
        const float* src = (const float*)W2v + base;
        float4 w0 = *(const float4*)src;
        float4 w1 = *(const float4*)(src + 4);
        u32x4 pk;
        pk.x = packbf(w0.x, w0.y);
        pk.y = packbf(w0.z, w0.w);
        pk.z = packbf(w1.x, w1.y);
        pk.w = packbf(w1.z, w1.w);
        *(u32x4*)&tile[row][c8] = pk;
      }
    }
    __syncthreads();
#pragma unroll
    for (int i = 0; i < 2; ++i) {
      int nrow = i * 32 + r;
      union { ushort_t us[8]; u32x4 v; } pk;
#pragma unroll
      for (int jj = 0; jj < 8; ++jj) pk.us[jj] = tile[c8 + jj][nrow];
      *(u32x4*)(W2T + (size_t)(nt * 64 + nrow) * D1 + kt * 64 + c8) = pk.v;
    }
  } else if (bid < 2336) {
    // ================= M0/M1 fold =================
    const int k = (bid - 2304) * 256 + t;
    float m0 = 0.f, m1 = 0.f;
    if (isbf) {
      const ushort_t* Wspu = (const ushort_t*)W_spv;
      const ushort_t* W1u = (const ushort_t*)W1v;
      for (int e = 0; e < ED; ++e) {
        float w = bf2f(W1u[e * D1 + k]);
        m0 += bf2f(Wspu[e]) * w;
        m1 += bf2f(Wspu[ED + e]) * w;
      }
    } else {
      const float* Wspf = (const float*)W_spv;
      const float* W1f = (const float*)W1v;
      for (int e = 0; e < ED; ++e) {
        float w = W1f[e * D1 + k];
        m0 += Wspf[e] * w;
        m1 += Wspf[ED + e] * w;
      }
    }
    M0[k] = m0;
    M1[k] = m1;
  } else {
    // ================= epf / b2f / flag =================
    if (t == 0) *flag = isbf;
    const ushort_t* epu = (const ushort_t*)end_posv;
    const float* epff = (const float*)end_posv;
    const ushort_t* b2u = (const ushort_t*)b2v;
    const float* b2ff = (const float*)b2v;
    for (int i = t; i < 1024; i += 256) {
      epf[i] = isbf ? bf2f(epu[i]) : epff[i];
      b2f[i] = isbf ? bf2f(b2u[i]) : b2ff[i];
    }
  }
}

// ---------------------------------------------------------------------------
// k_gemm (R11-proven, 335 us): fused A-gen + GEMM + max-pool epilogue.
// BM=64 BN=512 BK=64; grid 512: nb=bid&1, mb=bid>>1 (0..255).
// 4 waves, each 64m x 128n; 2 blocks/CU (VGPR-capped: 108 arch + 128 acc).
// B tile: DMA (global_load_lds w16) into unpadded [512][64] LDS, XOR swizzle
// applied on the GLOBAL fetch side (slot s of row r holds chunk s^(r&7)).
// ---------------------------------------------------------------------------
#define ASTR 72  // A-tile LDS row stride in shorts (144B)
__global__ __launch_bounds__(256, 2) void k_gemm(
    const ushort_t* __restrict__ hcb, const float* __restrict__ M0f,
    const float* __restrict__ M1f, const ushort_t* __restrict__ W2T,
    const float* __restrict__ epf, const float* __restrict__ b2f,
    const int* __restrict__ flag, void* __restrict__ outv) {
  __shared__ ushort_t aLds[64 * ASTR];   // 9.2 KB, padded
  __shared__ ushort_t bLds[512 * 64];    // 64 KB, unpadded (DMA dest), swizzled
  __shared__ float2 rrLds[64];

  const int t = threadIdx.x;
  const int w = t >> 6;
  const int lane = t & 63;
  const int nb = blockIdx.x & 1;
  const int mb = blockIdx.x >> 1;  // 0..255
  const int s = mb >> 4;
  const int abase = (mb & 15) * 2;
  const int isbf = *flag;

  if (t < 64) {
    int g = t >> 5, b = t & 31;
    int pa = s * 32 + abase + g, pb = s * 32 + b;
    float r0 = epf[pb * 2] - epf[pa * 2];
    float r1 = epf[pb * 2 + 1] - epf[pa * 2 + 1];
    rrLds[t] = make_float2(clip1(r0), clip1(r1));
  }
  __syncthreads();

  const int bq = t >> 3;  // 0..31 : hc row (b) this thread generates
  const int kc = t & 7;   // 0..7  : 8-short chunk within BK
  float rr0[2], rr1[2];
#pragma unroll
  for (int g = 0; g < 2; ++g) {
    float2 v = rrLds[g * 32 + bq];
    rr0[g] = v.x;
    rr1[g] = v.y;
  }

  const ushort_t* hcRow = hcb + (size_t)(s * 32 + bq) * D1 + kc * 8;
  const float* m0p = M0f + kc * 8;
  const float* m1p = M1f + kc * 8;

  // B DMA addressing: lane covers row (i*32 + w*8 + (lane>>3)), LDS slot lane&7,
  // so it must FETCH global chunk (lane&7) ^ (lane>>3).
  const int rowl = w * 8 + (lane >> 3);
  const int chl = (lane & 7) ^ (lane >> 3);
  const ushort_t* bGlob = W2T + (size_t)(nb * 512 + rowl) * D1 + chl * 8;
  ushort_t* bLdsLane = bLds + (size_t)rowl * 64 + (lane & 7) * 8;  // base + lane*16B

  ushort_t* aW = aLds + bq * ASTR + kc * 8;  // + g*32*ASTR

  f32x4 acc[4][8];
#pragma unroll
  for (int mt = 0; mt < 4; ++mt)
#pragma unroll
    for (int nt = 0; nt < 8; ++nt) acc[mt][nt] = (f32x4){0.f, 0.f, 0.f, 0.f};

  const int rl = lane & 15, q = lane >> 4, r7 = rl & 7;
  const ushort_t* aRbase = aLds + rl * ASTR + q * 8;          // + mt*16*ASTR + ki*32
  const ushort_t* bRbase = bLds + (w * 128 + rl) * 64;        // + nt*1024 + slot*8
  const int sl0 = (q ^ r7) * 8;        // ki=0: global chunk q
  const int sl1 = ((q + 4) ^ r7) * 8;  // ki=1: global chunk q+4

  for (int kk = 0; kk < D1 / 64; ++kk) {
    const int k0 = kk * 64;
    // ---- B tile: async DMA global->LDS (16B/lane, 16 issues) ----
#pragma unroll
    for (int i = 0; i < 16; ++i)
      async_load16(bGlob + (size_t)i * 32 * D1 + k0, bLdsLane + i * 32 * 64);

    // ---- A-gen: relu(hc + r0*M0 + r1*M1), pack bf16, write LDS ----
    u32x4 hv = *(const u32x4*)(hcRow + k0);
    float h0, h1, h2, h3, h4, h5, h6, h7;
    unpk(hv.x, h0, h1); unpk(hv.y, h2, h3);
    unpk(hv.z, h4, h5); unpk(hv.w, h6, h7);
    float4 a0 = *(const float4*)(m0p + k0);
    float4 a1 = *(const float4*)(m0p + k0 + 4);
    float4 c0 = *(const float4*)(m1p + k0);
    float4 c1 = *(const float4*)(m1p + k0 + 4);
#pragma unroll
    for (int g = 0; g < 2; ++g) {
      float r0 = rr0[g], r1 = rr1[g];
      float v0 = fmaxf(h0 + r0 * a0.x + r1 * c0.x, 0.f);
      float v1 = fmaxf(h1 + r0 * a0.y + r1 * c0.y, 0.f);
      float v2 = fmaxf(h2 + r0 * a0.z + r1 * c0.z, 0.f);
      float v3 = fmaxf(h3 + r0 * a0.w + r1 * c0.w, 0.f);
      float v4 = fmaxf(h4 + r0 * a1.x + r1 * c1.x, 0.f);
      float v5 = fmaxf(h5 + r0 * a1.y + r1 * c1.y, 0.f);
      float v6 = fmaxf(h6 + r0 * a1.z + r1 * c1.z, 0.f);
      float v7 = fmaxf(h7 + r0 * a1.w + r1 * c1.w, 0.f);
      u32x4 pk;
      pk.x = packbf(v0, v1);
      pk.y = packbf(v2, v3);
      pk.z = packbf(v4, v5);
      pk.w = packbf(v6, v7);
      *(u32x4*)(aW + g * 32 * ASTR) = pk;
    }
    __syncthreads();  // drains DMA (vmcnt) + A-gen ds_writes

    // ---- mfma phase ----
#pragma unroll
    for (int ki = 0; ki < 2; ++ki) {
      bf16x8 af[4], bfr[8];
#pragma unroll
      for (int mt = 0; mt < 4; ++mt)
        af[mt] = *(const bf16x8*)(aRbase + mt * 16 * ASTR + ki * 32);
      const int slk = ki ? sl1 : sl0;
#pragma unroll
      for (int nt = 0; nt < 8; ++nt)
        bfr[nt] = *(const bf16x8*)(bRbase + nt * 1024 + slk);
#pragma unroll
      for (int mt = 0; mt < 4; ++mt)
#pragma unroll
        for (int nt = 0; nt < 8; ++nt)
          acc[mt][nt] = __builtin_amdgcn_mfma_f32_16x16x32_bf16(
              af[mt], bfr[nt], acc[mt][nt], 0, 0, 0);
    }
    __syncthreads();
  }

  // ---- epilogue: max over b (32 m-rows/group), +b2, relu, store ----
#pragma unroll
  for (int g = 0; g < 2; ++g) {
    int orow = s * 32 + abase + g;
#pragma unroll
    for (int nt = 0; nt < 8; ++nt) {
      f32x4 x0 = acc[2 * g][nt], x1 = acc[2 * g + 1][nt];
      float v = fmaxf(fmaxf(fmaxf(x0.x, x0.y), fmaxf(x0.z, x0.w)),
                      fmaxf(fmaxf(x1.x, x1.y), fmaxf(x1.z, x1.w)));
      v = fmaxf(v, __shfl_xor(v, 16, 64));
      v = fmaxf(v, __shfl_xor(v, 32, 64));
      if (lane < 16) {
        int col = nb * 512 + w * 128 + nt * 16 + lane;
        float o = fmaxf(v + b2f[col], 0.f);
        if (isbf)
          ((ushort_t*)outv)[(size_t)orow * BOTN + col] = f2bf(o);
        else
          ((float*)outv)[(size_t)orow * BOTN + col] = o;
      }
    }
  }
}

extern "C" void kernel_launch(void* const* d_in, const int* in_sizes, int n_in,
                              void* d_out, int out_size, void* d_ws, size_t ws_size,
                              hipStream_t stream) {
  (void)in_sizes; (void)n_in; (void)out_size; (void)ws_size;
  const void* h_states = d_in[0];
  const void* end_pos = d_in[1];
  // d_in[2] rel_pos: unused by reference; d_in[3] seq_start_end: fixed equal scenes
  const void* W_sp = d_in[4];
  const void* b_sp = d_in[5];
  const void* W1 = d_in[6];
  const void* b1 = d_in[7];
  const void* W2 = d_in[8];
  const void* b2 = d_in[9];

  char* ws = (char*)d_ws;
  ushort_t* hcb = (ushort_t*)ws;                         // 8 MB  (512x8192 bf16)
  ushort_t* W2T = (ushort_t*)(ws + (8u << 20));          // 16 MB (1024x8192 bf16)
  float* M0f = (float*)(ws + (24u << 20));               // 32 KB
  float* M1f = (float*)(ws + (24u << 20) + 32768);       // 32 KB
  float* epf = (float*)(ws + (24u << 20) + 98304);       // 4 KB
  float* b2f = (float*)(ws + (24u << 20) + 102400);      // 4 KB
  int* flag = (int*)(ws + (24u << 20) + 106496);         // 4 B

  k_pre<<<dim3(2337), dim3(256), 0, stream>>>(
      h_states, end_pos, W_sp, b_sp, W1, b1, W2, b2,
      flag, epf, b2f, M0f, M1f, hcb, W2T);
  k_gemm<<<dim3(512), dim3(256), 0, stream>>>(hcb, M0f, M1f, W2T, epf, b2f, flag, d_out);
}